// Round 15
// baseline (229.169 us; speedup 1.0000x reference)
//
#include <hip/hip_runtime.h>
#include <hip/hip_bf16.h>
#include <cstdint>
#include <cstddef>

#define SLEN 2048
#define NHEAD 16
#define HDIM 64

typedef short bf16x8 __attribute__((ext_vector_type(8)));
typedef float f32x4 __attribute__((ext_vector_type(4)));

__device__ __forceinline__ unsigned short f2bf(float f) {
  union { __hip_bfloat16 b; unsigned short u; } cv;
  cv.b = __float2bfloat16(f);
  return cv.u;
}

// truncation pack: [p0, p1] -> bf16x2 in one u32 (2 VALU ops, no rounding)
__device__ __forceinline__ unsigned packtrunc(float a, float b) {
  union { float f; unsigned u; } ua, ub;
  ua.f = a; ub.f = b;
  return (ua.u >> 16) | (ub.u & 0xFFFF0000u);
}

__device__ __forceinline__ void async16(unsigned short* lds, const unsigned short* g) {
  __builtin_amdgcn_global_load_lds(
      (const __attribute__((address_space(1))) unsigned int*)g,
      (__attribute__((address_space(3))) unsigned int*)lds, 16, 0, 0);
}

// ---------------------------------------------------------------------------
// convert x (f32) -> bf16 flat
// ---------------------------------------------------------------------------
__global__ __launch_bounds__(256) void cvt_bf16(
    const float* __restrict__ in, unsigned short* __restrict__ out, int n8)
{
  int i = blockIdx.x * 256 + threadIdx.x;
  if (i >= n8) return;
  const float4 a = *(const float4*)(in + (size_t)i*8);
  const float4 b = *(const float4*)(in + (size_t)i*8 + 4);
  ushort4 o0 = {f2bf(a.x), f2bf(a.y), f2bf(a.z), f2bf(a.w)};
  ushort4 o1 = {f2bf(b.x), f2bf(b.y), f2bf(b.z), f2bf(b.w)};
  *(ushort4*)(out + (size_t)i*8)     = o0;
  *(ushort4*)(out + (size_t)i*8 + 4) = o1;
}

// ---------------------------------------------------------------------------
// mask (f32) -> mask * log2(e)  (exp2-domain softmax)
// ---------------------------------------------------------------------------
__global__ __launch_bounds__(256) void scale_mask(
    const float* __restrict__ in, float* __restrict__ out, int n)
{
  int i = blockIdx.x * 256 + threadIdx.x;
  if (i < n) out[i] = in[i] * 1.44269504088896f;
}

// ---------------------------------------------------------------------------
// transpose W (K,N) f32 -> Wt (N,K) bf16, 32x32 LDS tiles
// ---------------------------------------------------------------------------
__global__ __launch_bounds__(256) void transpose_w(
    const float* __restrict__ W, unsigned short* __restrict__ Wt, int K, int N)
{
  __shared__ unsigned short T[32][36];
  const int kb = blockIdx.y * 32, nb = blockIdx.x * 32;
  const int r = threadIdx.x >> 3, c4 = (threadIdx.x & 7) * 4;
  float4 w = *(const float4*)(W + (size_t)(kb + r)*N + nb + c4);
  T[c4+0][r] = f2bf(w.x); T[c4+1][r] = f2bf(w.y);
  T[c4+2][r] = f2bf(w.z); T[c4+3][r] = f2bf(w.w);
  __syncthreads();
  ushort4 o = {T[r][c4], T[r][c4+1], T[r][c4+2], T[r][c4+3]};
  *(ushort4*)(Wt + (size_t)(nb + r)*K + kb + c4) = o;
}

// ---------------------------------------------------------------------------
// GEMM1 (MFMA): qkv = xb @ WattnT^T + bias. BK=64 (half the barriers of
// BK=32), k-chunk XOR swizzle p^(row&7) for conflict-free b128 reads at
// 128-B row stride. Q-tiles scaled by 0.125*log2(e) (exp2-domain scores).
// ---------------------------------------------------------------------------
__global__ __launch_bounds__(256, 2) void gemm1_mfma(
    const unsigned short* __restrict__ Xb,
    const unsigned short* __restrict__ Wt,
    const float* __restrict__ Bias,
    unsigned short* __restrict__ Qb, unsigned short* __restrict__ Kb,
    unsigned short* __restrict__ Vt, int m0)
{
  __shared__ union {
    struct { unsigned short A[128*64]; unsigned short B[128*64]; } s;  // 32 KB
    unsigned short vt[128*136];                                        // 34.8 KB
  } u;
  const int tid = threadIdx.x;
  const int wid = tid >> 6, lane = tid & 63;
  const int lo = lane & 15, hi = lane >> 4;
  const int wr = wid >> 1, wc = wid & 1;
  const int mtile = blockIdx.y * 128;
  const int nbase = blockIdx.x * 128;

  f32x4 acc[4][4];
  #pragma unroll
  for (int i = 0; i < 4; i++)
    #pragma unroll
    for (int j = 0; j < 4; j++) { f32x4 z = {0.f,0.f,0.f,0.f}; acc[i][j] = z; }

  const unsigned short* Abase = Xb + (size_t)(m0 + mtile)*1024;
  const unsigned short* Bbase = Wt + (size_t)nbase*1024;
  const int x7 = lo & 7;

  for (int k0 = 0; k0 < 1024; k0 += 64) {
    __syncthreads();
    #pragma unroll
    for (int i = 0; i < 4; i++) {
      int ch = tid + i*256;                 // 0..1023
      int r = ch >> 3, p = ch & 7, c = p ^ (r & 7);
      async16(&u.s.A[r*64 + p*8], Abase + (size_t)r*1024 + k0 + c*8);
      async16(&u.s.B[r*64 + p*8], Bbase + (size_t)r*1024 + k0 + c*8);
    }
    __syncthreads();
    #pragma unroll
    for (int half = 0; half < 2; half++) {
      bf16x8 af[4], bf[4];
      #pragma unroll
      for (int mi = 0; mi < 4; mi++) {
        int row = wr*64 + mi*16 + lo;
        af[mi] = *(const bf16x8*)&u.s.A[row*64 + (((half*4 + hi) ^ x7))*8];
      }
      #pragma unroll
      for (int ni = 0; ni < 4; ni++) {
        int row = wc*64 + ni*16 + lo;
        bf[ni] = *(const bf16x8*)&u.s.B[row*64 + (((half*4 + hi) ^ x7))*8];
      }
      #pragma unroll
      for (int mi = 0; mi < 4; mi++)
        #pragma unroll
        for (int ni = 0; ni < 4; ni++)
          acc[mi][ni] = __builtin_amdgcn_mfma_f32_16x16x32_bf16(
              af[mi], bf[ni], acc[mi][ni], 0, 0, 0);
    }
  }

  float bias_[4];
  #pragma unroll
  for (int ni = 0; ni < 4; ni++) bias_[ni] = Bias[nbase + wc*64 + ni*16 + lo];

  const int bl = mtile >> 11;
  const int s0 = mtile & 2047;

  if (nbase < 2048) {
    unsigned short* dst = (nbase < 1024) ? Qb : Kb;
    const float sc = (nbase < 1024) ? 0.125f * 1.44269504088896f : 1.0f;
    const int nb2 = nbase & 1023;
    #pragma unroll
    for (int mi = 0; mi < 4; mi++)
      #pragma unroll
      for (int i = 0; i < 4; i++) {
        int s = s0 + wr*64 + mi*16 + hi*4 + i;
        #pragma unroll
        for (int ni = 0; ni < 4; ni++) {
          int n = nb2 + wc*64 + ni*16 + lo;
          int h = n >> 6, d = n & 63;
          dst[((size_t)(bl*16 + h)*SLEN + s)*HDIM + d] =
              f2bf((acc[mi][ni][i] + bias_[ni]) * sc);
        }
      }
  } else {
    __syncthreads();
    #pragma unroll
    for (int mi = 0; mi < 4; mi++)
      #pragma unroll
      for (int ni = 0; ni < 4; ni++)
        #pragma unroll
        for (int i = 0; i < 4; i++) {
          int ml = wr*64 + mi*16 + hi*4 + i;
          int nl = wc*64 + ni*16 + lo;
          u.vt[nl*136 + ml] = f2bf(acc[mi][ni][i] + bias_[ni]);
        }
    __syncthreads();
    const int rv = tid >> 1, halfc = (tid & 1)*64;
    const int ng = nbase - 2048 + rv;
    const int h = ng >> 6, d = ng & 63;
    unsigned short* drow = Vt + ((size_t)(bl*16 + h)*HDIM + d)*SLEN + s0 + halfc;
    #pragma unroll
    for (int j = 0; j < 8; j++) {
      bf16x8 v = *(const bf16x8*)&u.vt[rv*136 + halfc + j*8];
      *(bf16x8*)(drow + j*8) = v;
    }
  }
}

// ---------------------------------------------------------------------------
// MFMA flash attention v10: v8 + XCD swizzle; Ps writes packed to b64.
// ---------------------------------------------------------------------------
__global__ __launch_bounds__(256, 4) void attn_mfma(
    const unsigned short* __restrict__ Qb, const unsigned short* __restrict__ Kb,
    const unsigned short* __restrict__ Vt, const float* __restrict__ maskL,
    unsigned short* __restrict__ O, int b0)
{
  __shared__ unsigned short Ks[2][64*64];
  __shared__ unsigned short Vs[2][64*64];
  __shared__ unsigned short Ps[4][16][64];

  const int tid = threadIdx.x;
  const int wid = tid >> 6, lane = tid & 63;
  const int lo = lane & 15, hi = lane >> 4;

  // bijective XCD swizzle (gridDim.x = bc*256, always a multiple of 8)
  const int nwg = gridDim.x;
  const int swz = (blockIdx.x & 7) * (nwg >> 3) + (blockIdx.x >> 3);
  const int qt = swz & 15;                 // 128-row q tiles
  const int bh = swz >> 4;
  const int bglob = b0 + (bh >> 4);
  const float* mrow = maskL + (size_t)bglob * SLEN;

  const unsigned short* qg = Qb + ((size_t)bh*SLEN + qt*128)*HDIM;
  const unsigned short* kg = Kb + (size_t)bh*SLEN*HDIM;
  const unsigned short* vg = Vt + (size_t)bh*HDIM*SLEN;

  bf16x8 qa[2][2];
  #pragma unroll
  for (int g = 0; g < 2; g++) {
    const unsigned short* qrow = qg + (size_t)(g*64 + wid*16 + lo)*HDIM;
    qa[g][0] = *(const bf16x8*)(qrow + hi*8);
    qa[g][1] = *(const bf16x8*)(qrow + 32 + hi*8);
  }

  auto STAGE = [&](int bu, int kt2) {
    #pragma unroll
    for (int i = 0; i < 2; i++) {
      int slot = tid + i*256;
      int row = slot >> 3, p = slot & 7;
      int c = p ^ (row & 7);
      async16(&Ks[bu][row*64 + p*8], kg + (size_t)(kt2*64 + row)*HDIM + c*8);
      async16(&Vs[bu][row*64 + p*8], vg + (size_t)row*SLEN + kt2*64 + c*8);
    }
  };

  f32x4 lacc[2];
  f32x4 oacc[2][4];
  #pragma unroll
  for (int g = 0; g < 2; g++) {
    f32x4 z = {0.f,0.f,0.f,0.f};
    lacc[g] = z;
    #pragma unroll
    for (int i = 0; i < 4; i++) oacc[g][i] = z;
  }

  const bf16x8 ones = {0x3F80,0x3F80,0x3F80,0x3F80,0x3F80,0x3F80,0x3F80,0x3F80};
  const int x7 = lo & 7;
  const int pswz = (lo & 7) << 3;

  STAGE(0, 0);
  for (int kt = 0; kt < SLEN/64; kt++) {
    const int cur = kt & 1;
    __syncthreads();
    if (kt + 1 < SLEN/64) STAGE(cur ^ 1, kt + 1);

    // mask (pre-scaled by log2e) — shared by both q-groups, C-init of QK MFMA
    f32x4 mk4[4];
    #pragma unroll
    for (int blk = 0; blk < 4; blk++) {
      float4 mk = *(const float4*)(mrow + kt*64 + blk*16 + hi*4);
      mk4[blk][0] = mk.x; mk4[blk][1] = mk.y;
      mk4[blk][2] = mk.z; mk4[blk][3] = mk.w;
    }

    #pragma unroll
    for (int g = 0; g < 2; g++) {
      f32x4 sacc[4];
      __builtin_amdgcn_s_setprio(1);
      #pragma unroll
      for (int blk = 0; blk < 4; blk++) {
        const int row = blk*16 + lo;
        bf16x8 kb0 = *(const bf16x8*)&Ks[cur][row*64 + ((hi     ^ x7)*8)];
        bf16x8 kb1 = *(const bf16x8*)&Ks[cur][row*64 + (((hi+4) ^ x7)*8)];
        f32x4 z = __builtin_amdgcn_mfma_f32_16x16x32_bf16(kb0, qa[g][0], mk4[blk], 0, 0, 0);
        sacc[blk] = __builtin_amdgcn_mfma_f32_16x16x32_bf16(kb1, qa[g][1], z, 0, 0, 0);
      }
      __builtin_amdgcn_s_setprio(0);

      // p = exp2(score), truncation-packed, b64 Ps writes (4 per group)
      #pragma unroll
      for (int blk = 0; blk < 4; blk++) {
        float p0 = exp2f(sacc[blk][0]);
        float p1 = exp2f(sacc[blk][1]);
        float p2 = exp2f(sacc[blk][2]);
        float p3 = exp2f(sacc[blk][3]);
        uint2 w = {packtrunc(p0, p1), packtrunc(p2, p3)};
        *(uint2*)&Ps[wid][lo][(blk*16 + hi*4) ^ pswz] = w;
      }

      bf16x8 pa0 = *(const bf16x8*)&Ps[wid][lo][(hi*8)      ^ pswz];
      bf16x8 pa1 = *(const bf16x8*)&Ps[wid][lo][(32 + hi*8) ^ pswz];

      lacc[g] = __builtin_amdgcn_mfma_f32_16x16x32_bf16(pa0, ones, lacc[g], 0, 0, 0);
      lacc[g] = __builtin_amdgcn_mfma_f32_16x16x32_bf16(pa1, ones, lacc[g], 0, 0, 0);

      __builtin_amdgcn_s_setprio(1);
      #pragma unroll
      for (int dblk = 0; dblk < 4; dblk++) {
        const int row = dblk*16 + lo;
        bf16x8 vb0 = *(const bf16x8*)&Vs[cur][row*64 + ((hi     ^ x7)*8)];
        bf16x8 vb1 = *(const bf16x8*)&Vs[cur][row*64 + (((hi+4) ^ x7)*8)];
        oacc[g][dblk] = __builtin_amdgcn_mfma_f32_16x16x32_bf16(pa0, vb0, oacc[g][dblk], 0, 0, 0);
        oacc[g][dblk] = __builtin_amdgcn_mfma_f32_16x16x32_bf16(pa1, vb1, oacc[g][dblk], 0, 0, 0);
      }
      __builtin_amdgcn_s_setprio(0);
    }
  }

  #pragma unroll
  for (int g = 0; g < 2; g++) {
    const size_t obase = ((size_t)bh*SLEN + qt*128 + g*64 + wid*16)*HDIM;
    #pragma unroll
    for (int i = 0; i < 4; i++) {
      float inv = 1.f / lacc[g][i];
      int row = hi*4 + i;
      #pragma unroll
      for (int dblk = 0; dblk < 4; dblk++)
        O[obase + (size_t)row*HDIM + dblk*16 + lo] = f2bf(oacc[g][dblk][i]*inv);
    }
  }
}

// ---------------------------------------------------------------------------
// GEMM2 (MFMA): out = merge_heads(Ob) @ WprojT^T + bias. BK=64 (one head
// per K-step), k-chunk XOR swizzle, half the barriers.
// ---------------------------------------------------------------------------
__global__ __launch_bounds__(256, 2) void gemm2_mfma(
    const unsigned short* __restrict__ Ob,
    const unsigned short* __restrict__ Wt,
    const float* __restrict__ Bias,
    float* __restrict__ Out, int m0)
{
  __shared__ unsigned short As[128*64];
  __shared__ unsigned short Bs[128*64];
  const int tid = threadIdx.x;
  const int wid = tid >> 6, lane = tid & 63;
  const int lo = lane & 15, hi = lane >> 4;
  const int wr = wid >> 1, wc = wid & 1;
  const int mtile = blockIdx.y * 128;
  const int nbase = blockIdx.x * 128;

  f32x4 acc[4][4];
  #pragma unroll
  for (int i = 0; i < 4; i++)
    #pragma unroll
    for (int j = 0; j < 4; j++) { f32x4 z = {0.f,0.f,0.f,0.f}; acc[i][j] = z; }

  const int bl = mtile >> 11;
  const int s0 = mtile & 2047;
  const unsigned short* Bbase = Wt + (size_t)nbase*1024;
  const int x7 = lo & 7;

  for (int k0 = 0; k0 < 1024; k0 += 64) {
    const int h = k0 >> 6;
    const unsigned short* Agbase = Ob + ((size_t)(bl*16 + h)*SLEN + s0)*HDIM;
    __syncthreads();
    #pragma unroll
    for (int i = 0; i < 4; i++) {
      int ch = tid + i*256;
      int r = ch >> 3, p = ch & 7, c = p ^ (r & 7);
      async16(&As[r*64 + p*8], Agbase + (size_t)r*HDIM + c*8);
      async16(&Bs[r*64 + p*8], Bbase + (size_t)r*1024 + k0 + c*8);
    }
    __syncthreads();
    #pragma unroll
    for (int half = 0; half < 2; half++) {
      bf16x8 af[4], bf[4];
      #pragma unroll
      for (int mi = 0; mi < 4; mi++) {
        int row = wr*64 + mi*16 + lo;
        af[mi] = *(const bf16x8*)&As[row*64 + (((half*4 + hi) ^ x7))*8];
      }
      #pragma unroll
      for (int ni = 0; ni < 4; ni++) {
        int row = wc*64 + ni*16 + lo;
        bf[ni] = *(const bf16x8*)&Bs[row*64 + (((half*4 + hi) ^ x7))*8];
      }
      #pragma unroll
      for (int mi = 0; mi < 4; mi++)
        #pragma unroll
        for (int ni = 0; ni < 4; ni++)
          acc[mi][ni] = __builtin_amdgcn_mfma_f32_16x16x32_bf16(
              af[mi], bf[ni], acc[mi][ni], 0, 0, 0);
    }
  }

  float bias_[4];
  #pragma unroll
  for (int ni = 0; ni < 4; ni++) bias_[ni] = Bias[nbase + wc*64 + ni*16 + lo];

  #pragma unroll
  for (int mi = 0; mi < 4; mi++)
    #pragma unroll
    for (int i = 0; i < 4; i++) {
      int m = m0 + mtile + wr*64 + mi*16 + hi*4 + i;
      float* orow = Out + (size_t)m*1024 + nbase + wc*64 + lo;
      #pragma unroll
      for (int ni = 0; ni < 4; ni++)
        orow[ni*16] = acc[mi][ni][i] + bias_[ni];
    }
}

extern "C" void kernel_launch(void* const* d_in, const int* in_sizes, int n_in,
                              void* d_out, int out_size, void* d_ws, size_t ws_size,
                              hipStream_t stream) {
  const float* x     = (const float*)d_in[0];
  const float* amask = (const float*)d_in[1];
  const float* wat   = (const float*)d_in[2];
  const float* bat   = (const float*)d_in[3];
  const float* wpr   = (const float*)d_in[4];
  const float* bpr   = (const float*)d_in[5];
  float* out = (float*)d_out;

  unsigned short* WattnT = (unsigned short*)d_ws;
  unsigned short* WprojT = WattnT + (size_t)3072*1024;
  unsigned short* xb     = WprojT + (size_t)1024*1024;
  float*          maskL  = (float*)(xb + (size_t)8192*1024);
  unsigned short* chunk0 = (unsigned short*)(maskL + 4*SLEN);

  const size_t PB = (size_t)NHEAD * SLEN * HDIM;
  const size_t base_bytes = ((size_t)3072*1024 + (size_t)1024*1024 + (size_t)8192*1024) * 2
                          + (size_t)4*SLEN*4;
  int bc = 1;
  if (ws_size >= base_bytes + 4 * 4 * PB * 2)      bc = 4;
  else if (ws_size >= base_bytes + 2 * 4 * PB * 2) bc = 2;

  cvt_bf16<<<dim3((8192*1024/8 + 255)/256), dim3(256), 0, stream>>>(
      x, xb, 8192*1024/8);
  scale_mask<<<dim3((4*SLEN + 255)/256), dim3(256), 0, stream>>>(
      amask, maskL, 4*SLEN);
  transpose_w<<<dim3(3072/32, 1024/32), dim3(256), 0, stream>>>(wat, WattnT, 1024, 3072);
  transpose_w<<<dim3(1024/32, 1024/32), dim3(256), 0, stream>>>(wpr, WprojT, 1024, 1024);

  for (int b0 = 0; b0 < 4; b0 += bc) {
    unsigned short* Qb = chunk0;
    unsigned short* Kb = Qb + (size_t)bc * PB;
    unsigned short* Vt = Kb + (size_t)bc * PB;
    unsigned short* Ob = Vt + (size_t)bc * PB;
    int Mrows = bc * SLEN;
    gemm1_mfma<<<dim3(24, Mrows/128), dim3(256), 0, stream>>>(
        xb, WattnT, bat, Qb, Kb, Vt, b0 * SLEN);
    attn_mfma<<<dim3(bc * NHEAD * (SLEN/128)), dim3(256), 0, stream>>>(
        Qb, Kb, Vt, maskL, Ob, b0);
    gemm2_mfma<<<dim3(8, Mrows/128), dim3(256), 0, stream>>>(
        Ob, WprojT, bpr, out, b0 * SLEN);
  }
}

// Round 16
// 226.892 us; speedup vs baseline: 1.0100x; 1.0100x over previous
//
#include <hip/hip_runtime.h>
#include <hip/hip_bf16.h>
#include <cstdint>
#include <cstddef>

#define SLEN 2048
#define NHEAD 16
#define HDIM 64

typedef short bf16x8 __attribute__((ext_vector_type(8)));
typedef float f32x4 __attribute__((ext_vector_type(4)));

__device__ __forceinline__ unsigned short f2bf(float f) {
  union { __hip_bfloat16 b; unsigned short u; } cv;
  cv.b = __float2bfloat16(f);
  return cv.u;
}

// truncation pack: [p0, p1] -> bf16x2 in one u32 (2 VALU ops, no rounding)
__device__ __forceinline__ unsigned packtrunc(float a, float b) {
  union { float f; unsigned u; } ua, ub;
  ua.f = a; ub.f = b;
  return (ua.u >> 16) | (ub.u & 0xFFFF0000u);
}

__device__ __forceinline__ void async16(unsigned short* lds, const unsigned short* g) {
  __builtin_amdgcn_global_load_lds(
      (const __attribute__((address_space(1))) unsigned int*)g,
      (__attribute__((address_space(3))) unsigned int*)lds, 16, 0, 0);
}

// ---------------------------------------------------------------------------
// convert x (f32) -> bf16 flat
// ---------------------------------------------------------------------------
__global__ __launch_bounds__(256) void cvt_bf16(
    const float* __restrict__ in, unsigned short* __restrict__ out, int n8)
{
  int i = blockIdx.x * 256 + threadIdx.x;
  if (i >= n8) return;
  const float4 a = *(const float4*)(in + (size_t)i*8);
  const float4 b = *(const float4*)(in + (size_t)i*8 + 4);
  ushort4 o0 = {f2bf(a.x), f2bf(a.y), f2bf(a.z), f2bf(a.w)};
  ushort4 o1 = {f2bf(b.x), f2bf(b.y), f2bf(b.z), f2bf(b.w)};
  *(ushort4*)(out + (size_t)i*8)     = o0;
  *(ushort4*)(out + (size_t)i*8 + 4) = o1;
}

// ---------------------------------------------------------------------------
// mask (f32) -> mask * log2(e)  (exp2-domain softmax)
// ---------------------------------------------------------------------------
__global__ __launch_bounds__(256) void scale_mask(
    const float* __restrict__ in, float* __restrict__ out, int n)
{
  int i = blockIdx.x * 256 + threadIdx.x;
  if (i < n) out[i] = in[i] * 1.44269504088896f;
}

// ---------------------------------------------------------------------------
// transpose W (K,N) f32 -> Wt (N,K) bf16, 32x32 LDS tiles
// ---------------------------------------------------------------------------
__global__ __launch_bounds__(256) void transpose_w(
    const float* __restrict__ W, unsigned short* __restrict__ Wt, int K, int N)
{
  __shared__ unsigned short T[32][36];
  const int kb = blockIdx.y * 32, nb = blockIdx.x * 32;
  const int r = threadIdx.x >> 3, c4 = (threadIdx.x & 7) * 4;
  float4 w = *(const float4*)(W + (size_t)(kb + r)*N + nb + c4);
  T[c4+0][r] = f2bf(w.x); T[c4+1][r] = f2bf(w.y);
  T[c4+2][r] = f2bf(w.z); T[c4+3][r] = f2bf(w.w);
  __syncthreads();
  ushort4 o = {T[r][c4], T[r][c4+1], T[r][c4+2], T[r][c4+3]};
  *(ushort4*)(Wt + (size_t)(nb + r)*K + kb + c4) = o;
}

// ---------------------------------------------------------------------------
// GEMM1 (MFMA): qkv = xb @ WattnT^T + bias. BK=32 (round-14 best form).
// Q-tiles scaled by 0.125*log2(e) so scores come out of MFMA in exp2 domain.
// ---------------------------------------------------------------------------
__global__ __launch_bounds__(256, 2) void gemm1_mfma(
    const unsigned short* __restrict__ Xb,
    const unsigned short* __restrict__ Wt,
    const float* __restrict__ Bias,
    unsigned short* __restrict__ Qb, unsigned short* __restrict__ Kb,
    unsigned short* __restrict__ Vt, int m0)
{
  __shared__ union {
    struct { unsigned short A[128*32]; unsigned short B[128*32]; } s;
    unsigned short vt[128*136];
  } u;
  const int tid = threadIdx.x;
  const int wid = tid >> 6, lane = tid & 63;
  const int lo = lane & 15, hi = lane >> 4;
  const int wr = wid >> 1, wc = wid & 1;
  const int mtile = blockIdx.y * 128;
  const int nbase = blockIdx.x * 128;

  f32x4 acc[4][4];
  #pragma unroll
  for (int i = 0; i < 4; i++)
    #pragma unroll
    for (int j = 0; j < 4; j++) { f32x4 z = {0.f,0.f,0.f,0.f}; acc[i][j] = z; }

  const int ldrow = 32*wid + (lane >> 2);
  const int koff  = (lane & 3) * 8;

  const unsigned short* Abase = Xb + (size_t)(m0 + mtile)*1024;
  const unsigned short* Bbase = Wt + (size_t)nbase*1024;

  for (int k0 = 0; k0 < 1024; k0 += 32) {
    __syncthreads();
    #pragma unroll
    for (int cc = 0; cc < 2; cc++) {
      int r = ldrow + cc*16;
      async16(&u.s.A[r*32 + koff], Abase + (size_t)r*1024 + k0 + koff);
      async16(&u.s.B[r*32 + koff], Bbase + (size_t)r*1024 + k0 + koff);
    }
    __syncthreads();
    bf16x8 af[4], bf[4];
    #pragma unroll
    for (int mi = 0; mi < 4; mi++)
      af[mi] = *(const bf16x8*)&u.s.A[(wr*64 + mi*16 + lo)*32 + hi*8];
    #pragma unroll
    for (int ni = 0; ni < 4; ni++)
      bf[ni] = *(const bf16x8*)&u.s.B[(wc*64 + ni*16 + lo)*32 + hi*8];
    #pragma unroll
    for (int mi = 0; mi < 4; mi++)
      #pragma unroll
      for (int ni = 0; ni < 4; ni++)
        acc[mi][ni] = __builtin_amdgcn_mfma_f32_16x16x32_bf16(
            af[mi], bf[ni], acc[mi][ni], 0, 0, 0);
  }

  float bias_[4];
  #pragma unroll
  for (int ni = 0; ni < 4; ni++) bias_[ni] = Bias[nbase + wc*64 + ni*16 + lo];

  const int bl = mtile >> 11;
  const int s0 = mtile & 2047;

  if (nbase < 2048) {
    unsigned short* dst = (nbase < 1024) ? Qb : Kb;
    const float sc = (nbase < 1024) ? 0.125f * 1.44269504088896f : 1.0f;
    const int nb2 = nbase & 1023;
    #pragma unroll
    for (int mi = 0; mi < 4; mi++)
      #pragma unroll
      for (int i = 0; i < 4; i++) {
        int s = s0 + wr*64 + mi*16 + hi*4 + i;
        #pragma unroll
        for (int ni = 0; ni < 4; ni++) {
          int n = nb2 + wc*64 + ni*16 + lo;
          int h = n >> 6, d = n & 63;
          dst[((size_t)(bl*16 + h)*SLEN + s)*HDIM + d] =
              f2bf((acc[mi][ni][i] + bias_[ni]) * sc);
        }
      }
  } else {
    __syncthreads();
    #pragma unroll
    for (int mi = 0; mi < 4; mi++)
      #pragma unroll
      for (int ni = 0; ni < 4; ni++)
        #pragma unroll
        for (int i = 0; i < 4; i++) {
          int ml = wr*64 + mi*16 + hi*4 + i;
          int nl = wc*64 + ni*16 + lo;
          u.vt[nl*136 + ml] = f2bf(acc[mi][ni][i] + bias_[ni]);
        }
    __syncthreads();
    const int rv = tid >> 1, halfc = (tid & 1)*64;
    const int ng = nbase - 2048 + rv;
    const int h = ng >> 6, d = ng & 63;
    unsigned short* drow = Vt + ((size_t)(bl*16 + h)*HDIM + d)*SLEN + s0 + halfc;
    #pragma unroll
    for (int j = 0; j < 8; j++) {
      bf16x8 v = *(const bf16x8*)&u.vt[rv*136 + halfc + j*8];
      *(bf16x8*)(drow + j*8) = v;
    }
  }
}

// ---------------------------------------------------------------------------
// MFMA flash attention v10 (round-15 best): v8 + XCD swizzle + b64 Ps writes.
// ---------------------------------------------------------------------------
__global__ __launch_bounds__(256, 4) void attn_mfma(
    const unsigned short* __restrict__ Qb, const unsigned short* __restrict__ Kb,
    const unsigned short* __restrict__ Vt, const float* __restrict__ maskL,
    unsigned short* __restrict__ O, int b0)
{
  __shared__ unsigned short Ks[2][64*64];
  __shared__ unsigned short Vs[2][64*64];
  __shared__ unsigned short Ps[4][16][64];

  const int tid = threadIdx.x;
  const int wid = tid >> 6, lane = tid & 63;
  const int lo = lane & 15, hi = lane >> 4;

  // bijective XCD swizzle (gridDim.x = bc*256, always a multiple of 8)
  const int nwg = gridDim.x;
  const int swz = (blockIdx.x & 7) * (nwg >> 3) + (blockIdx.x >> 3);
  const int qt = swz & 15;                 // 128-row q tiles
  const int bh = swz >> 4;
  const int bglob = b0 + (bh >> 4);
  const float* mrow = maskL + (size_t)bglob * SLEN;

  const unsigned short* qg = Qb + ((size_t)bh*SLEN + qt*128)*HDIM;
  const unsigned short* kg = Kb + (size_t)bh*SLEN*HDIM;
  const unsigned short* vg = Vt + (size_t)bh*HDIM*SLEN;

  bf16x8 qa[2][2];
  #pragma unroll
  for (int g = 0; g < 2; g++) {
    const unsigned short* qrow = qg + (size_t)(g*64 + wid*16 + lo)*HDIM;
    qa[g][0] = *(const bf16x8*)(qrow + hi*8);
    qa[g][1] = *(const bf16x8*)(qrow + 32 + hi*8);
  }

  auto STAGE = [&](int bu, int kt2) {
    #pragma unroll
    for (int i = 0; i < 2; i++) {
      int slot = tid + i*256;
      int row = slot >> 3, p = slot & 7;
      int c = p ^ (row & 7);
      async16(&Ks[bu][row*64 + p*8], kg + (size_t)(kt2*64 + row)*HDIM + c*8);
      async16(&Vs[bu][row*64 + p*8], vg + (size_t)row*SLEN + kt2*64 + c*8);
    }
  };

  f32x4 lacc[2];
  f32x4 oacc[2][4];
  #pragma unroll
  for (int g = 0; g < 2; g++) {
    f32x4 z = {0.f,0.f,0.f,0.f};
    lacc[g] = z;
    #pragma unroll
    for (int i = 0; i < 4; i++) oacc[g][i] = z;
  }

  const bf16x8 ones = {0x3F80,0x3F80,0x3F80,0x3F80,0x3F80,0x3F80,0x3F80,0x3F80};
  const int x7 = lo & 7;
  const int pswz = (lo & 7) << 3;

  STAGE(0, 0);
  for (int kt = 0; kt < SLEN/64; kt++) {
    const int cur = kt & 1;
    __syncthreads();
    if (kt + 1 < SLEN/64) STAGE(cur ^ 1, kt + 1);

    // mask (pre-scaled by log2e) — shared by both q-groups, C-init of QK MFMA
    f32x4 mk4[4];
    #pragma unroll
    for (int blk = 0; blk < 4; blk++) {
      float4 mk = *(const float4*)(mrow + kt*64 + blk*16 + hi*4);
      mk4[blk][0] = mk.x; mk4[blk][1] = mk.y;
      mk4[blk][2] = mk.z; mk4[blk][3] = mk.w;
    }

    #pragma unroll
    for (int g = 0; g < 2; g++) {
      f32x4 sacc[4];
      __builtin_amdgcn_s_setprio(1);
      #pragma unroll
      for (int blk = 0; blk < 4; blk++) {
        const int row = blk*16 + lo;
        bf16x8 kb0 = *(const bf16x8*)&Ks[cur][row*64 + ((hi     ^ x7)*8)];
        bf16x8 kb1 = *(const bf16x8*)&Ks[cur][row*64 + (((hi+4) ^ x7)*8)];
        f32x4 z = __builtin_amdgcn_mfma_f32_16x16x32_bf16(kb0, qa[g][0], mk4[blk], 0, 0, 0);
        sacc[blk] = __builtin_amdgcn_mfma_f32_16x16x32_bf16(kb1, qa[g][1], z, 0, 0, 0);
      }
      __builtin_amdgcn_s_setprio(0);

      // p = exp2(score), truncation-packed, b64 Ps writes (4 per group)
      #pragma unroll
      for (int blk = 0; blk < 4; blk++) {
        float p0 = exp2f(sacc[blk][0]);
        float p1 = exp2f(sacc[blk][1]);
        float p2 = exp2f(sacc[blk][2]);
        float p3 = exp2f(sacc[blk][3]);
        uint2 w = {packtrunc(p0, p1), packtrunc(p2, p3)};
        *(uint2*)&Ps[wid][lo][(blk*16 + hi*4) ^ pswz] = w;
      }

      bf16x8 pa0 = *(const bf16x8*)&Ps[wid][lo][(hi*8)      ^ pswz];
      bf16x8 pa1 = *(const bf16x8*)&Ps[wid][lo][(32 + hi*8) ^ pswz];

      lacc[g] = __builtin_amdgcn_mfma_f32_16x16x32_bf16(pa0, ones, lacc[g], 0, 0, 0);
      lacc[g] = __builtin_amdgcn_mfma_f32_16x16x32_bf16(pa1, ones, lacc[g], 0, 0, 0);

      __builtin_amdgcn_s_setprio(1);
      #pragma unroll
      for (int dblk = 0; dblk < 4; dblk++) {
        const int row = dblk*16 + lo;
        bf16x8 vb0 = *(const bf16x8*)&Vs[cur][row*64 + ((hi     ^ x7)*8)];
        bf16x8 vb1 = *(const bf16x8*)&Vs[cur][row*64 + (((hi+4) ^ x7)*8)];
        oacc[g][dblk] = __builtin_amdgcn_mfma_f32_16x16x32_bf16(pa0, vb0, oacc[g][dblk], 0, 0, 0);
        oacc[g][dblk] = __builtin_amdgcn_mfma_f32_16x16x32_bf16(pa1, vb1, oacc[g][dblk], 0, 0, 0);
      }
      __builtin_amdgcn_s_setprio(0);
    }
  }

  #pragma unroll
  for (int g = 0; g < 2; g++) {
    const size_t obase = ((size_t)bh*SLEN + qt*128 + g*64 + wid*16)*HDIM;
    #pragma unroll
    for (int i = 0; i < 4; i++) {
      float inv = 1.f / lacc[g][i];
      int row = hi*4 + i;
      #pragma unroll
      for (int dblk = 0; dblk < 4; dblk++)
        O[obase + (size_t)row*HDIM + dblk*16 + lo] = f2bf(oacc[g][dblk][i]*inv);
    }
  }
}

// ---------------------------------------------------------------------------
// GEMM2 (MFMA): out = merge_heads(Ob) @ WprojT^T + bias. (round-14/BK=32 form)
// ---------------------------------------------------------------------------
__global__ __launch_bounds__(256, 2) void gemm2_mfma(
    const unsigned short* __restrict__ Ob,
    const unsigned short* __restrict__ Wt,
    const float* __restrict__ Bias,
    float* __restrict__ Out, int m0)
{
  __shared__ unsigned short As[128*32];
  __shared__ unsigned short Bs[128*32];
  const int tid = threadIdx.x;
  const int wid = tid >> 6, lane = tid & 63;
  const int lo = lane & 15, hi = lane >> 4;
  const int wr = wid >> 1, wc = wid & 1;
  const int mtile = blockIdx.y * 128;
  const int nbase = blockIdx.x * 128;

  f32x4 acc[4][4];
  #pragma unroll
  for (int i = 0; i < 4; i++)
    #pragma unroll
    for (int j = 0; j < 4; j++) { f32x4 z = {0.f,0.f,0.f,0.f}; acc[i][j] = z; }

  const int ldrow = 32*wid + (lane >> 2);
  const int koff  = (lane & 3) * 8;

  const int bl = mtile >> 11;
  const int s0 = mtile & 2047;
  const unsigned short* Bbase = Wt + (size_t)nbase*1024;

  for (int k0 = 0; k0 < 1024; k0 += 32) {
    const int h = k0 >> 6;
    const int dpart = (k0 & 63) + koff;
    __syncthreads();
    #pragma unroll
    for (int cc = 0; cc < 2; cc++) {
      int r = ldrow + cc*16;
      const unsigned short* ga =
          Ob + ((size_t)(bl*16 + h)*SLEN + s0 + r)*HDIM + dpart;
      async16(&As[r*32 + koff], ga);
      async16(&Bs[r*32 + koff], Bbase + (size_t)r*1024 + k0 + koff);
    }
    __syncthreads();
    bf16x8 af[4], bf[4];
    #pragma unroll
    for (int mi = 0; mi < 4; mi++)
      af[mi] = *(const bf16x8*)&As[(wr*64 + mi*16 + lo)*32 + hi*8];
    #pragma unroll
    for (int ni = 0; ni < 4; ni++)
      bf[ni] = *(const bf16x8*)&Bs[(wc*64 + ni*16 + lo)*32 + hi*8];
    #pragma unroll
    for (int mi = 0; mi < 4; mi++)
      #pragma unroll
      for (int ni = 0; ni < 4; ni++)
        acc[mi][ni] = __builtin_amdgcn_mfma_f32_16x16x32_bf16(
            af[mi], bf[ni], acc[mi][ni], 0, 0, 0);
  }

  float bias_[4];
  #pragma unroll
  for (int ni = 0; ni < 4; ni++) bias_[ni] = Bias[nbase + wc*64 + ni*16 + lo];

  #pragma unroll
  for (int mi = 0; mi < 4; mi++)
    #pragma unroll
    for (int i = 0; i < 4; i++) {
      int m = m0 + mtile + wr*64 + mi*16 + hi*4 + i;
      float* orow = Out + (size_t)m*1024 + nbase + wc*64 + lo;
      #pragma unroll
      for (int ni = 0; ni < 4; ni++)
        orow[ni*16] = acc[mi][ni][i] + bias_[ni];
    }
}

extern "C" void kernel_launch(void* const* d_in, const int* in_sizes, int n_in,
                              void* d_out, int out_size, void* d_ws, size_t ws_size,
                              hipStream_t stream) {
  const float* x     = (const float*)d_in[0];
  const float* amask = (const float*)d_in[1];
  const float* wat   = (const float*)d_in[2];
  const float* bat   = (const float*)d_in[3];
  const float* wpr   = (const float*)d_in[4];
  const float* bpr   = (const float*)d_in[5];
  float* out = (float*)d_out;

  unsigned short* WattnT = (unsigned short*)d_ws;
  unsigned short* WprojT = WattnT + (size_t)3072*1024;
  unsigned short* xb     = WprojT + (size_t)1024*1024;
  float*          maskL  = (float*)(xb + (size_t)8192*1024);
  unsigned short* chunk0 = (unsigned short*)(maskL + 4*SLEN);

  const size_t PB = (size_t)NHEAD * SLEN * HDIM;
  const size_t base_bytes = ((size_t)3072*1024 + (size_t)1024*1024 + (size_t)8192*1024) * 2
                          + (size_t)4*SLEN*4;
  int bc = 1;
  if (ws_size >= base_bytes + 4 * 4 * PB * 2)      bc = 4;
  else if (ws_size >= base_bytes + 2 * 4 * PB * 2) bc = 2;

  cvt_bf16<<<dim3((8192*1024/8 + 255)/256), dim3(256), 0, stream>>>(
      x, xb, 8192*1024/8);
  scale_mask<<<dim3((4*SLEN + 255)/256), dim3(256), 0, stream>>>(
      amask, maskL, 4*SLEN);
  transpose_w<<<dim3(3072/32, 1024/32), dim3(256), 0, stream>>>(wat, WattnT, 1024, 3072);
  transpose_w<<<dim3(1024/32, 1024/32), dim3(256), 0, stream>>>(wpr, WprojT, 1024, 1024);

  for (int b0 = 0; b0 < 4; b0 += bc) {
    unsigned short* Qb = chunk0;
    unsigned short* Kb = Qb + (size_t)bc * PB;
    unsigned short* Vt = Kb + (size_t)bc * PB;
    unsigned short* Ob = Vt + (size_t)bc * PB;
    int Mrows = bc * SLEN;
    gemm1_mfma<<<dim3(24, Mrows/128), dim3(256), 0, stream>>>(
        xb, WattnT, bat, Qb, Kb, Vt, b0 * SLEN);
    attn_mfma<<<dim3(bc * NHEAD * (SLEN/128)), dim3(256), 0, stream>>>(
        Qb, Kb, Vt, maskL, Ob, b0);
    gemm2_mfma<<<dim3(8, Mrows/128), dim3(256), 0, stream>>>(
        Ob, WprojT, bpr, out, b0 * SLEN);
  }
}